// Round 4
// baseline (401.362 us; speedup 1.0000x reference)
//
#include <hip/hip_runtime.h>
#include <stdint.h>

// ---------------------------------------------------------------------------
// DkNN round 8: prune-then-rescore.
//  - prep_all: bf16-hi conversion only (Bh, Ah) + exact fp32 norms; computes
//    per-query ||Al||, ||A|| and global max ||B||, ||Bl|| for a RIGOROUS
//    approximation error bound (Cauchy-Schwarz on the dropped split terms).
//  - mfma_tile: 1-pass Ah*Bh GEMM (4 K-steps instead of 12), records the
//    per-(query, 16-train-row group) minimum of s = xn2 - 2*dot (q2 constant
//    per query -> dropped; ranking unchanged).
//  - select_classify: per query, find global approx min, rescore all rows in
//    groups within WINDOW = 2*(2*errdot)+1e-3 of it in EXACT fp32 (strictly
//    more accurate than the old 3-pass split), then fused conformal classify.
// Expected ~1-3 candidate groups/query for this data; any count is correct.
// ---------------------------------------------------------------------------

typedef __attribute__((ext_vector_type(8))) short short8;   // 8 bf16 = 4 VGPR
typedef __attribute__((ext_vector_type(4))) float float4v;  // MFMA C/D

static __device__ __forceinline__ unsigned short bf16_rn(float f) {
    unsigned int u = __float_as_uint(f);
    unsigned int r = (u + 0x7FFFu + ((u >> 16) & 1u)) >> 16;
    return (unsigned short)r;
}

static __device__ __forceinline__ void gload_lds16(const void* g, void* l) {
    __builtin_amdgcn_global_load_lds(
        (const __attribute__((address_space(1))) unsigned int*)g,
        (__attribute__((address_space(3))) unsigned int*)l, 16, 0, 0);
}

// blocks [0, train_blocks): grid-stride train conversion; [train_blocks, +Mp):
// one query row each.
__global__ void prep_all(const float* __restrict__ X, const float* __restrict__ x,
                         const float* __restrict__ center,
                         unsigned short* __restrict__ Bh, float* __restrict__ xn2,
                         unsigned short* __restrict__ Ah, float* __restrict__ xqf,
                         float* __restrict__ q2a, float* __restrict__ al2q,
                         unsigned int* __restrict__ scal,
                         int nb_train, int Np, int B, int Mp, int train_blocks) {
    const int tid = threadIdx.x;
    if (blockIdx.x < (unsigned)train_blocks) {
        const int lane = tid & 63;
        const int wv   = tid >> 6;
        const int nquads = Np >> 2;
        float lmaxb2 = 0.f, lmaxbl2 = 0.f;
        for (int quad = blockIdx.x; quad < nquads; quad += train_blocks) {
            const int row = quad * 4 + wv;
            if (row >= nb_train) {
                ushort4 z = make_ushort4(0, 0, 0, 0);
                *(ushort4*)(Bh + (size_t)row * 256 + lane * 4) = z;
                if (lane == 0) xn2[row] = 3.0e38f;
            } else {
                float4 v = ((const float4*)(X + (size_t)row * 256))[lane];
                ushort4 h;
                h.x = bf16_rn(v.x); h.y = bf16_rn(v.y);
                h.z = bf16_rn(v.z); h.w = bf16_rn(v.w);
                *(ushort4*)(Bh + (size_t)row * 256 + lane * 4) = h;
                float lx = v.x - __uint_as_float((unsigned)h.x << 16);
                float ly = v.y - __uint_as_float((unsigned)h.y << 16);
                float lz = v.z - __uint_as_float((unsigned)h.z << 16);
                float lw = v.w - __uint_as_float((unsigned)h.w << 16);
                float ss  = v.x * v.x + v.y * v.y + v.z * v.z + v.w * v.w;
                float bl2 = lx * lx + ly * ly + lz * lz + lw * lw;
                #pragma unroll
                for (int s = 1; s < 64; s <<= 1) {
                    ss  += __shfl_xor(ss, s);
                    bl2 += __shfl_xor(bl2, s);
                }
                if (lane == 0) {
                    xn2[row] = ss;
                    lmaxb2  = fmaxf(lmaxb2, ss);
                    lmaxbl2 = fmaxf(lmaxbl2, bl2);
                }
            }
        }
        if (lane == 0 && lmaxb2 > 0.f) {
            atomicMax(scal + 0, __float_as_uint(lmaxb2));
            atomicMax(scal + 1, __float_as_uint(lmaxbl2));
        }
        return;
    }
    // ---- query side: one row per block, 256 threads (d=256) ----
    int row = blockIdx.x - train_blocks;
    if (row >= Mp) return;
    if (row >= B) {
        Ah[(size_t)row * 256 + tid] = 0;
        xqf[(size_t)row * 256 + tid] = 0.f;
        if (tid == 0) { q2a[row] = 0.f; al2q[row] = 0.f; }
        return;
    }
    float v = x[(size_t)row * 256 + tid];
    float ss = v * v;
    #pragma unroll
    for (int s = 1; s < 64; s <<= 1) ss += __shfl_xor(ss, s);
    __shared__ float p1[4], p2[4], p3[4];
    if ((tid & 63) == 0) p1[tid >> 6] = ss;
    __syncthreads();
    float tot = p1[0] + p1[1] + p1[2] + p1[3];
    float inv = 1.0f / sqrtf(tot);
    float val = v * inv - center[tid];
    unsigned short hb = bf16_rn(val);
    float hf = __uint_as_float((unsigned int)hb << 16);
    float al = val - hf;
    Ah[(size_t)row * 256 + tid] = hb;
    xqf[(size_t)row * 256 + tid] = val;
    float ss2 = val * val, sal = al * al;
    #pragma unroll
    for (int s = 1; s < 64; s <<= 1) {
        ss2 += __shfl_xor(ss2, s);
        sal += __shfl_xor(sal, s);
    }
    if ((tid & 63) == 0) { p2[tid >> 6] = ss2; p3[tid >> 6] = sal; }
    __syncthreads();
    if (tid == 0) {
        q2a[row]  = p2[0] + p2[1] + p2[2] + p2[3];
        al2q[row] = p3[0] + p3[1] + p3[2] + p3[3];
    }
}

// 128x128 tile, 4 waves each computing a 64x64 quadrant (4x4 frags of 16x16x32).
// Single pass Ah*Bh, 4 K-steps of BK=64. Epilogue: per-(query, 16-col group)
// min of s = xn2 - 2*dot, stored to gmin (exclusive ownership, plain stores).
__global__ __launch_bounds__(256, 4) void mfma_tile(
    const unsigned short* __restrict__ Adata,  // Ah, Mp*256
    const unsigned short* __restrict__ Bdata,  // Bh, Np*256
    const float* __restrict__ xn2,
    float* __restrict__ gmin,
    int Mp, int Np, int nb_train, int B,
    int ntiles, int nper, int mtiles)
{
    __shared__ unsigned short As[128 * 64];   // [row][chunk ^ (row&7)] 16B chunks
    __shared__ unsigned short Bs[128 * 64];

    const int bid = blockIdx.x;
    const int xcd = bid & 7;
    const int s_  = bid >> 3;
    const int n_t = xcd * nper + (s_ / mtiles);
    const int m_t = s_ - (s_ / mtiles) * mtiles;
    if (n_t >= ntiles) return;
    const int mtile = m_t * 128;
    const int ntile = n_t * 128;

    const int tid  = threadIdx.x;
    const int wave = tid >> 6;
    const int lane = tid & 63;

    // ---- staging role: waves 0,1 stage A rows [0:64),[64:128); waves 2,3 for B
    const int isB   = wave >> 1;
    const int Rwave = (wave & 1) * 64;
    const int lrow8  = lane >> 3;
    const int lchunk = lane & 7;
    const unsigned short* sbase = isB
        ? (Bdata + (size_t)(ntile + Rwave + lrow8) * 256 + (size_t)((lchunk ^ lrow8) * 8))
        : (Adata + (size_t)(mtile + Rwave + lrow8) * 256 + (size_t)((lchunk ^ lrow8) * 8));
    unsigned short* lwave = (isB ? Bs : As) + Rwave * 64;

    // ---- compute role: quadrant
    const int mq = (wave >> 1) * 64;
    const int nq = (wave & 1) * 64;
    const int lrow = lane & 15;
    const int kseg = lane >> 4;
    const int sw = lrow & 7;

    float4v acc[4][4];
    #pragma unroll
    for (int i = 0; i < 4; ++i)
        #pragma unroll
        for (int j = 0; j < 4; ++j)
            acc[i][j] = (float4v){0.f, 0.f, 0.f, 0.f};

    for (int s = 0; s < 4; ++s) {
        const unsigned short* g = sbase + (size_t)(s * 64);
        __syncthreads();
        #pragma unroll
        for (int q = 0; q < 8; ++q)
            gload_lds16(g + q * 2048, lwave + q * 512);
        __syncthreads();
        #pragma unroll
        for (int t = 0; t < 2; ++t) {
            const int wch = ((t * 4 + kseg) ^ sw) * 8;
            short8 a[4], b[4];
            #pragma unroll
            for (int i = 0; i < 4; ++i)
                a[i] = *(const short8*)&As[(mq + i * 16 + lrow) * 64 + wch];
            #pragma unroll
            for (int j = 0; j < 4; ++j)
                b[j] = *(const short8*)&Bs[(nq + j * 16 + lrow) * 64 + wch];
            #pragma unroll
            for (int i = 0; i < 4; ++i)
                #pragma unroll
                for (int j = 0; j < 4; ++j)
                    acc[i][j] = __builtin_amdgcn_mfma_f32_16x16x32_bf16(
                        a[i], b[j], acc[i][j], 0, 0, 0);
        }
    }

    // ---- epilogue: per-(q, 16-col group) min of xn2 - 2*dot ----
    const int ng = Np >> 4;
    const int gbase = (ntile >> 4) + (nq >> 4);   // this wave's 4 groups
    float xnv[4];
    #pragma unroll
    for (int j = 0; j < 4; ++j)
        xnv[j] = xn2[ntile + nq + j * 16 + lrow];   // pads hold 3e38

    #pragma unroll
    for (int i = 0; i < 4; ++i) {
        #pragma unroll
        for (int r = 0; r < 4; ++r) {
            const int lm = mq + i * 16 + kseg * 4 + r;   // block-local query
            const int gq = mtile + lm;
            float v[4];
            #pragma unroll
            for (int j = 0; j < 4; ++j)
                v[j] = xnv[j] - 2.0f * acc[i][j][r];
            #pragma unroll
            for (int sft = 1; sft < 16; sft <<= 1) {
                #pragma unroll
                for (int j = 0; j < 4; ++j)
                    v[j] = fminf(v[j], __shfl_xor(v[j], sft));
            }
            if (lrow == 0 && gq < B) {
                float4 f4 = make_float4(v[0], v[1], v[2], v[3]);
                *(float4*)&gmin[(size_t)gq * ng + gbase] = f4;
            }
        }
    }
}

// One block per query: load per-group approx minima into LDS, compute window
// from the rigorous error bound, rescore candidate groups in exact fp32,
// then fused conformal classification (wave 0).
__global__ __launch_bounds__(256) void select_classify(
    const float* __restrict__ gmin, const float* __restrict__ xqf,
    const float* __restrict__ X, const float* __restrict__ xn2,
    const float* __restrict__ q2a, const float* __restrict__ al2q,
    const unsigned int* __restrict__ scal,
    const int* __restrict__ labels, const int* __restrict__ nbr,
    const int* __restrict__ cali, float* __restrict__ out,
    int Np, int nb_train, int knm1, int nb_cali, int B)
{
    extern __shared__ float gbuf[];            // ng floats
    __shared__ float xq_s[256];
    __shared__ float wmin[4], fsc[4];
    __shared__ int   fid[4];
    __shared__ float s_thr;
    __shared__ int   s_closest;

    const int q    = blockIdx.x;
    const int tid  = threadIdx.x;
    const int lane = tid & 63;
    const int wave = tid >> 6;
    const int ng   = Np >> 4;

    float vmin = 3.4e38f;
    for (int i = tid; i < ng; i += 256) {
        float v = gmin[(size_t)q * ng + i];
        gbuf[i] = v;
        vmin = fminf(vmin, v);
    }
    #pragma unroll
    for (int s = 1; s < 64; s <<= 1) vmin = fminf(vmin, __shfl_xor(vmin, s));
    if (lane == 0) wmin[wave] = vmin;
    xq_s[tid] = xqf[(size_t)q * 256 + tid];
    __syncthreads();
    if (tid == 0) {
        float m = fminf(fminf(wmin[0], wmin[1]), fminf(wmin[2], wmin[3]));
        float maxb  = sqrtf(__uint_as_float(scal[0]));
        float maxbl = sqrtf(__uint_as_float(scal[1]));
        float an = sqrtf(q2a[q]), al = sqrtf(al2q[q]);
        float errdot = al * maxb + an * maxbl + al * maxbl;
        s_thr = m + 4.0f * errdot + 1e-3f;
    }
    __syncthreads();
    const float thr = s_thr;

    // scan + exact rescore. 4 lanes per row (rsub = dim quarter), 16 rows/group.
    const int rsub = lane & 3;
    const int rrow = lane >> 2;
    float bsc = 3.4e38f; int bidx = 0x7FFFFFFF;
    for (int base = wave * 64; base < ng; base += 256) {
        const int g = base + lane;
        bool hit = (g < ng) && (gbuf[g] <= thr);
        unsigned long long mask = __ballot(hit);
        while (mask) {
            int b = __ffsll((unsigned long long)mask) - 1;
            mask &= mask - 1;
            int row = (base + b) * 16 + rrow;
            if (row < nb_train) {
                const float* xr = X + (size_t)row * 256 + rsub * 64;
                const float* xs = xq_s + rsub * 64;
                float dot = 0.f;
                #pragma unroll
                for (int k = 0; k < 16; ++k) {
                    float4 a4 = *(const float4*)(xs + k * 4);
                    float4 b4 = *(const float4*)(xr + k * 4);
                    dot += a4.x * b4.x + a4.y * b4.y + a4.z * b4.z + a4.w * b4.w;
                }
                dot += __shfl_xor(dot, 1);
                dot += __shfl_xor(dot, 2);
                float sc = xn2[row] - 2.0f * dot;
                if (sc < bsc || (sc == bsc && row < bidx)) { bsc = sc; bidx = row; }
            }
        }
    }
    #pragma unroll
    for (int s = 1; s < 64; s <<= 1) {
        float osc = __shfl_xor(bsc, s);
        int   oid = __shfl_xor(bidx, s);
        if (osc < bsc || (osc == bsc && oid < bidx)) { bsc = osc; bidx = oid; }
    }
    if (lane == 0) { fsc[wave] = bsc; fid[wave] = bidx; }
    __syncthreads();
    if (tid == 0) {
        float bs = fsc[0]; int bi = fid[0];
        #pragma unroll
        for (int w = 1; w < 4; ++w)
            if (fsc[w] < bs || (fsc[w] == bs && fid[w] < bi)) { bs = fsc[w]; bi = fid[w]; }
        s_closest = bi;
    }
    __syncthreads();

    if (wave == 0) {
        const int closest = s_closest;
        const int K = knm1 + 1;   // 75
        int lbl0 = -1, lbl1 = -1;
        if (lane < K) {
            int idx = (lane == 0) ? closest : nbr[(size_t)closest * knm1 + (lane - 1)];
            lbl0 = labels[idx];
        }
        int j2 = lane + 64;
        if (j2 < K) {
            int idx = nbr[(size_t)closest * knm1 + (j2 - 1)];
            lbl1 = labels[idx];
        }
        int bestc = 0, bestp = -1;
        #pragma unroll
        for (int c = 0; c < 10; ++c) {
            int cnt = __popcll(__ballot(lbl0 == c)) + __popcll(__ballot(lbl1 == c));
            int v = K - cnt;
            int lo = 0, hi = nb_cali;
            while (lo < hi) {             // bisect_left
                int mid = (lo + hi) >> 1;
                if (cali[mid] < v) lo = mid + 1; else hi = mid;
            }
            int p = nb_cali - lo;
            if (p > bestp) { bestp = p; bestc = c; }
        }
        float pv = (float)bestp / (float)nb_cali;
        if (lane < 10)
            out[(size_t)q * 10 + lane] = (lane == bestc) ? pv : 0.0f;
    }
}

extern "C" void kernel_launch(void* const* d_in, const int* in_sizes, int n_in,
                              void* d_out, int out_size, void* d_ws, size_t ws_size,
                              hipStream_t stream) {
    const float* x      = (const float*)d_in[0];
    const float* X      = (const float*)d_in[1];
    const float* center = (const float*)d_in[2];
    const int* labels   = (const int*)d_in[3];
    const int* nbr      = (const int*)d_in[4];
    const int* cali     = (const int*)d_in[5];
    float* out = (float*)d_out;

    const int d        = in_sizes[2];              // 256
    const int B        = in_sizes[0] / d;          // 1024
    const int nb_train = in_sizes[3];              // 100000
    const int knm1     = in_sizes[4] / nb_train;   // 74
    const int nb_cali  = in_sizes[5];              // 1000

    const int Mp = (B + 127) & ~127;               // 1024
    const int Np = (nb_train + 127) & ~127;        // 100096
    const int ng = Np >> 4;                        // 6256

    char* ws = (char*)d_ws;
    size_t off = 0;
    float* gmin = (float*)(ws + off);          off += (size_t)Mp * ng * 4;
    unsigned short* Ah = (unsigned short*)(ws + off); off += (size_t)Mp * 256 * 2;
    float* xqf  = (float*)(ws + off);          off += (size_t)Mp * 256 * 4;
    float* q2a  = (float*)(ws + off);          off += (size_t)Mp * 4;
    float* al2q = (float*)(ws + off);          off += (size_t)Mp * 4;
    unsigned short* Bh = (unsigned short*)(ws + off); off += (size_t)Np * 256 * 2;
    float* xn2  = (float*)(ws + off);          off += (size_t)Np * 4;
    unsigned int* scal = (unsigned int*)(ws + off); off += 8;

    hipMemsetAsync(scal, 0, 8, stream);

    const int train_blocks = 1024;
    prep_all<<<train_blocks + Mp, 256, 0, stream>>>(
        X, x, center, Bh, xn2, Ah, xqf, q2a, al2q, scal,
        nb_train, Np, B, Mp, train_blocks);

    const int ntiles = Np / 128;                   // 782
    const int mtiles = Mp / 128;                   // 8
    const int nper   = (ntiles + 7) / 8;           // 98
    mfma_tile<<<8 * nper * mtiles, 256, 0, stream>>>(
        Ah, Bh, xn2, gmin, Mp, Np, nb_train, B, ntiles, nper, mtiles);

    select_classify<<<B, 256, ng * 4, stream>>>(
        gmin, xqf, X, xn2, q2a, al2q, scal, labels, nbr, cali, out,
        Np, nb_train, knm1, nb_cali, B);
}

// Round 5
// 339.670 us; speedup vs baseline: 1.1816x; 1.1816x over previous
//
#include <hip/hip_runtime.h>
#include <stdint.h>

// ---------------------------------------------------------------------------
// DkNN round 9: prune-then-rescore, throughput-shaped prep.
//  - prep_all (train): 1 block per 16 rows; each thread owns 16 contiguous
//    floats -> 4 independent float4 loads in flight (latency fix for the
//    131us/800GB/s prep of round 8). No Bl pass: ||Bl|| <= 2^-8 ||B||
//    (bf16 round-to-nearest, rigorous), so only xn2 + global max||B|| needed.
//  - mfma_tile: 1-pass Ah*Bh GEMM (4 K-steps), per-(query, 64-col group)
//    minima -> gmin is 6.4 MB (4x smaller), epilogue stores 4x fewer.
//  - select_classify: window = 4*errdot + 1e-3 slack, candidate queue (cap
//    256, brute-force fallback), exact fp32 rescore, fused conformal
//    classification.
// ---------------------------------------------------------------------------

typedef __attribute__((ext_vector_type(8))) short short8;   // 8 bf16 = 4 VGPR
typedef __attribute__((ext_vector_type(4))) float float4v;  // MFMA C/D

static __device__ __forceinline__ unsigned short bf16_rn(float f) {
    unsigned int u = __float_as_uint(f);
    unsigned int r = (u + 0x7FFFu + ((u >> 16) & 1u)) >> 16;
    return (unsigned short)r;
}

static __device__ __forceinline__ void gload_lds16(const void* g, void* l) {
    __builtin_amdgcn_global_load_lds(
        (const __attribute__((address_space(1))) unsigned int*)g,
        (__attribute__((address_space(3))) unsigned int*)l, 16, 0, 0);
}

// blocks [0, train_rb): 16 train rows each; [train_rb, +Mp): one query row.
__global__ __launch_bounds__(256) void prep_all(
    const float* __restrict__ X, const float* __restrict__ x,
    const float* __restrict__ center,
    unsigned short* __restrict__ Bh, float* __restrict__ xn2,
    unsigned short* __restrict__ Ah, float* __restrict__ xqf,
    float* __restrict__ q2a, float* __restrict__ al2q,
    unsigned int* __restrict__ scal,
    int nb_train, int Np, int B, int Mp, int train_rb)
{
    const int tid = threadIdx.x;
    __shared__ float smax[16];
    __shared__ float p1[4], p2[4], p3[4];

    if ((int)blockIdx.x < train_rb) {
        // ---- train side: row r = blk*16 + tid/16, 16 floats per thread ----
        const int r   = blockIdx.x * 16 + (tid >> 4);
        const int seg = tid & 15;
        if (r >= nb_train) {
            ushort4 z = make_ushort4(0, 0, 0, 0);
            ushort4* bp = (ushort4*)(Bh + (size_t)r * 256 + seg * 16);
            bp[0] = z; bp[1] = z; bp[2] = z; bp[3] = z;
            if (seg == 0) { xn2[r] = 3.0e38f; smax[tid >> 4] = 0.f; }
        } else {
            const float* xr = X + (size_t)r * 256 + seg * 16;
            float4 v0 = ((const float4*)xr)[0];
            float4 v1 = ((const float4*)xr)[1];
            float4 v2 = ((const float4*)xr)[2];
            float4 v3 = ((const float4*)xr)[3];
            ushort4 h0, h1, h2, h3;
            h0.x = bf16_rn(v0.x); h0.y = bf16_rn(v0.y); h0.z = bf16_rn(v0.z); h0.w = bf16_rn(v0.w);
            h1.x = bf16_rn(v1.x); h1.y = bf16_rn(v1.y); h1.z = bf16_rn(v1.z); h1.w = bf16_rn(v1.w);
            h2.x = bf16_rn(v2.x); h2.y = bf16_rn(v2.y); h2.z = bf16_rn(v2.z); h2.w = bf16_rn(v2.w);
            h3.x = bf16_rn(v3.x); h3.y = bf16_rn(v3.y); h3.z = bf16_rn(v3.z); h3.w = bf16_rn(v3.w);
            ushort4* bp = (ushort4*)(Bh + (size_t)r * 256 + seg * 16);
            bp[0] = h0; bp[1] = h1; bp[2] = h2; bp[3] = h3;
            float ss = v0.x * v0.x + v0.y * v0.y + v0.z * v0.z + v0.w * v0.w
                     + v1.x * v1.x + v1.y * v1.y + v1.z * v1.z + v1.w * v1.w
                     + v2.x * v2.x + v2.y * v2.y + v2.z * v2.z + v2.w * v2.w
                     + v3.x * v3.x + v3.y * v3.y + v3.z * v3.z + v3.w * v3.w;
            ss += __shfl_xor(ss, 1);
            ss += __shfl_xor(ss, 2);
            ss += __shfl_xor(ss, 4);
            ss += __shfl_xor(ss, 8);
            if (seg == 0) { xn2[r] = ss; smax[tid >> 4] = ss; }
        }
        __syncthreads();
        if (tid == 0) {
            float m = smax[0];
            #pragma unroll
            for (int i = 1; i < 16; ++i) m = fmaxf(m, smax[i]);
            if (m > 0.f) atomicMax(scal, __float_as_uint(m));
        }
        return;
    }
    // ---- query side: one row per block, 256 threads (d=256) ----
    int row = blockIdx.x - train_rb;
    if (row >= Mp) return;
    if (row >= B) {
        Ah[(size_t)row * 256 + tid] = 0;
        xqf[(size_t)row * 256 + tid] = 0.f;
        if (tid == 0) { q2a[row] = 0.f; al2q[row] = 0.f; }
        return;
    }
    float v = x[(size_t)row * 256 + tid];
    float ss = v * v;
    #pragma unroll
    for (int s = 1; s < 64; s <<= 1) ss += __shfl_xor(ss, s);
    if ((tid & 63) == 0) p1[tid >> 6] = ss;
    __syncthreads();
    float tot = p1[0] + p1[1] + p1[2] + p1[3];
    float inv = 1.0f / sqrtf(tot);
    float val = v * inv - center[tid];
    unsigned short hb = bf16_rn(val);
    float hf = __uint_as_float((unsigned int)hb << 16);
    float al = val - hf;
    Ah[(size_t)row * 256 + tid] = hb;
    xqf[(size_t)row * 256 + tid] = val;
    float ss2 = val * val, sal = al * al;
    #pragma unroll
    for (int s = 1; s < 64; s <<= 1) {
        ss2 += __shfl_xor(ss2, s);
        sal += __shfl_xor(sal, s);
    }
    if ((tid & 63) == 0) { p2[tid >> 6] = ss2; p3[tid >> 6] = sal; }
    __syncthreads();
    if (tid == 0) {
        q2a[row]  = p2[0] + p2[1] + p2[2] + p2[3];
        al2q[row] = p3[0] + p3[1] + p3[2] + p3[3];
    }
}

// 128x128 tile, 4 waves each computing a 64x64 quadrant (4x4 frags of 16x16x32).
// Single pass Ah*Bh, 4 K-steps of BK=64. Epilogue: per-(query, 64-col group)
// min of xn2 - 2*dot -> gmin (exclusive ownership, scalar stores).
__global__ __launch_bounds__(256, 4) void mfma_tile(
    const unsigned short* __restrict__ Adata,  // Ah, Mp*256
    const unsigned short* __restrict__ Bdata,  // Bh, Np*256
    const float* __restrict__ xn2,
    float* __restrict__ gmin,
    int Mp, int Np, int nb_train, int B,
    int ntiles, int nper, int mtiles)
{
    __shared__ unsigned short As[128 * 64];   // [row][chunk ^ (row&7)] 16B chunks
    __shared__ unsigned short Bs[128 * 64];

    const int bid = blockIdx.x;
    const int xcd = bid & 7;
    const int s_  = bid >> 3;
    const int n_t = xcd * nper + (s_ / mtiles);
    const int m_t = s_ - (s_ / mtiles) * mtiles;
    if (n_t >= ntiles) return;
    const int mtile = m_t * 128;
    const int ntile = n_t * 128;

    const int tid  = threadIdx.x;
    const int wave = tid >> 6;
    const int lane = tid & 63;

    // ---- staging role: waves 0,1 stage A rows [0:64),[64:128); waves 2,3 for B
    const int isB   = wave >> 1;
    const int Rwave = (wave & 1) * 64;
    const int lrow8  = lane >> 3;
    const int lchunk = lane & 7;
    const unsigned short* sbase = isB
        ? (Bdata + (size_t)(ntile + Rwave + lrow8) * 256 + (size_t)((lchunk ^ lrow8) * 8))
        : (Adata + (size_t)(mtile + Rwave + lrow8) * 256 + (size_t)((lchunk ^ lrow8) * 8));
    unsigned short* lwave = (isB ? Bs : As) + Rwave * 64;

    // ---- compute role: quadrant
    const int mq = (wave >> 1) * 64;
    const int nq = (wave & 1) * 64;
    const int lrow = lane & 15;
    const int kseg = lane >> 4;
    const int sw = lrow & 7;

    float4v acc[4][4];
    #pragma unroll
    for (int i = 0; i < 4; ++i)
        #pragma unroll
        for (int j = 0; j < 4; ++j)
            acc[i][j] = (float4v){0.f, 0.f, 0.f, 0.f};

    for (int s = 0; s < 4; ++s) {
        const unsigned short* g = sbase + (size_t)(s * 64);
        __syncthreads();
        #pragma unroll
        for (int q = 0; q < 8; ++q)
            gload_lds16(g + q * 2048, lwave + q * 512);
        __syncthreads();
        #pragma unroll
        for (int t = 0; t < 2; ++t) {
            const int wch = ((t * 4 + kseg) ^ sw) * 8;
            short8 a[4], b[4];
            #pragma unroll
            for (int i = 0; i < 4; ++i)
                a[i] = *(const short8*)&As[(mq + i * 16 + lrow) * 64 + wch];
            #pragma unroll
            for (int j = 0; j < 4; ++j)
                b[j] = *(const short8*)&Bs[(nq + j * 16 + lrow) * 64 + wch];
            #pragma unroll
            for (int i = 0; i < 4; ++i)
                #pragma unroll
                for (int j = 0; j < 4; ++j)
                    acc[i][j] = __builtin_amdgcn_mfma_f32_16x16x32_bf16(
                        a[i], b[j], acc[i][j], 0, 0, 0);
        }
    }

    // ---- epilogue: per-(q, 64-col group) min of xn2 - 2*dot ----
    const int ng64 = Np >> 6;
    const int gb = (ntile + nq) >> 6;       // this wave's group index
    float xnv[4];
    #pragma unroll
    for (int j = 0; j < 4; ++j)
        xnv[j] = xn2[ntile + nq + j * 16 + lrow];   // pads hold 3e38

    #pragma unroll
    for (int i = 0; i < 4; ++i) {
        #pragma unroll
        for (int r = 0; r < 4; ++r) {
            const int lm = mq + i * 16 + kseg * 4 + r;   // block-local query
            const int gq = mtile + lm;
            float vm = fminf(
                fminf(xnv[0] - 2.0f * acc[i][0][r], xnv[1] - 2.0f * acc[i][1][r]),
                fminf(xnv[2] - 2.0f * acc[i][2][r], xnv[3] - 2.0f * acc[i][3][r]));
            #pragma unroll
            for (int sft = 1; sft < 16; sft <<= 1)
                vm = fminf(vm, __shfl_xor(vm, sft));
            if (lrow == 0 && gq < B)
                gmin[(size_t)gq * ng64 + gb] = vm;
        }
    }
}

// One block per query: approx minima -> window from rigorous bound -> exact
// fp32 rescore of candidate 64-row groups -> fused conformal classification.
__global__ __launch_bounds__(256) void select_classify(
    const float* __restrict__ gmin, const float* __restrict__ xqf,
    const float* __restrict__ X, const float* __restrict__ xn2,
    const float* __restrict__ q2a, const float* __restrict__ al2q,
    const unsigned int* __restrict__ scal,
    const int* __restrict__ labels, const int* __restrict__ nbr,
    const int* __restrict__ cali, float* __restrict__ out,
    int Np, int nb_train, int knm1, int nb_cali, int B)
{
    extern __shared__ float gbuf[];            // ng64 floats
    __shared__ float xq_s[256];
    __shared__ float wmin[4], fsc[4];
    __shared__ int   fid[4];
    __shared__ float s_thr;
    __shared__ int   cand[256];
    __shared__ int   s_ncand;
    __shared__ int   s_closest;

    const int q    = blockIdx.x;
    const int tid  = threadIdx.x;
    const int lane = tid & 63;
    const int wave = tid >> 6;
    const int ng64 = Np >> 6;

    if (tid == 0) s_ncand = 0;
    xq_s[tid] = xqf[(size_t)q * 256 + tid];
    float vmin = 3.4e38f;
    for (int i = tid; i < ng64; i += 256) {
        float v = gmin[(size_t)q * ng64 + i];
        gbuf[i] = v;
        vmin = fminf(vmin, v);
    }
    #pragma unroll
    for (int s = 1; s < 64; s <<= 1) vmin = fminf(vmin, __shfl_xor(vmin, s));
    if (lane == 0) wmin[wave] = vmin;
    __syncthreads();
    if (tid == 0) {
        float m = fminf(fminf(wmin[0], wmin[1]), fminf(wmin[2], wmin[3]));
        float maxb  = sqrtf(__uint_as_float(scal[0]));
        float maxbl = maxb * 0.00390625f;          // ||Bl|| <= 2^-8 ||B||, rigorous
        float an = sqrtf(q2a[q]), al = sqrtf(al2q[q]);
        float errdot = al * maxb * 1.00390625f + (an + al) * maxbl;
        s_thr = m + 4.0f * errdot + 1e-3f;
    }
    __syncthreads();
    const float thr = s_thr;
    for (int g = tid; g < ng64; g += 256) {
        if (gbuf[g] <= thr) {
            int p = atomicAdd(&s_ncand, 1);
            if (p < 256) cand[p] = g;
        }
    }
    __syncthreads();
    const int nc = s_ncand;

    // exact rescore: 4 lanes per row (dim quarters), 64 rows per group.
    const int rsub = tid & 3;
    const int rrow = tid >> 2;
    float bsc = 3.4e38f; int bidx = 0x7FFFFFFF;
    auto rescore = [&](int g) {
        int row = g * 64 + rrow;
        if (row < nb_train) {
            const float* xr = X + (size_t)row * 256 + rsub * 64;
            const float* xs = xq_s + rsub * 64;
            float dot = 0.f;
            #pragma unroll
            for (int k = 0; k < 16; ++k) {
                float4 a4 = *(const float4*)(xs + k * 4);
                float4 b4 = *(const float4*)(xr + k * 4);
                dot += a4.x * b4.x + a4.y * b4.y + a4.z * b4.z + a4.w * b4.w;
            }
            dot += __shfl_xor(dot, 1);
            dot += __shfl_xor(dot, 2);
            float sc = xn2[row] - 2.0f * dot;
            if (sc < bsc || (sc == bsc && row < bidx)) { bsc = sc; bidx = row; }
        }
    };
    if (nc <= 256) {
        for (int c = 0; c < nc; ++c) rescore(cand[c]);
    } else {
        for (int g = 0; g < ng64; ++g)
            if (gbuf[g] <= thr) rescore(g);      // correctness backstop
    }
    #pragma unroll
    for (int s = 1; s < 64; s <<= 1) {
        float osc = __shfl_xor(bsc, s);
        int   oid = __shfl_xor(bidx, s);
        if (osc < bsc || (osc == bsc && oid < bidx)) { bsc = osc; bidx = oid; }
    }
    if (lane == 0) { fsc[wave] = bsc; fid[wave] = bidx; }
    __syncthreads();
    if (tid == 0) {
        float bs = fsc[0]; int bi = fid[0];
        #pragma unroll
        for (int w = 1; w < 4; ++w)
            if (fsc[w] < bs || (fsc[w] == bs && fid[w] < bi)) { bs = fsc[w]; bi = fid[w]; }
        s_closest = bi;
    }
    __syncthreads();

    if (wave == 0) {
        const int closest = s_closest;
        const int K = knm1 + 1;   // 75
        int lbl0 = -1, lbl1 = -1;
        if (lane < K) {
            int idx = (lane == 0) ? closest : nbr[(size_t)closest * knm1 + (lane - 1)];
            lbl0 = labels[idx];
        }
        int j2 = lane + 64;
        if (j2 < K) {
            int idx = nbr[(size_t)closest * knm1 + (j2 - 1)];
            lbl1 = labels[idx];
        }
        int bestc = 0, bestp = -1;
        #pragma unroll
        for (int c = 0; c < 10; ++c) {
            int cnt = __popcll(__ballot(lbl0 == c)) + __popcll(__ballot(lbl1 == c));
            int v = K - cnt;
            int lo = 0, hi = nb_cali;
            while (lo < hi) {             // bisect_left
                int mid = (lo + hi) >> 1;
                if (cali[mid] < v) lo = mid + 1; else hi = mid;
            }
            int p = nb_cali - lo;
            if (p > bestp) { bestp = p; bestc = c; }
        }
        float pv = (float)bestp / (float)nb_cali;
        if (lane < 10)
            out[(size_t)q * 10 + lane] = (lane == bestc) ? pv : 0.0f;
    }
}

extern "C" void kernel_launch(void* const* d_in, const int* in_sizes, int n_in,
                              void* d_out, int out_size, void* d_ws, size_t ws_size,
                              hipStream_t stream) {
    const float* x      = (const float*)d_in[0];
    const float* X      = (const float*)d_in[1];
    const float* center = (const float*)d_in[2];
    const int* labels   = (const int*)d_in[3];
    const int* nbr      = (const int*)d_in[4];
    const int* cali     = (const int*)d_in[5];
    float* out = (float*)d_out;

    const int d        = in_sizes[2];              // 256
    const int B        = in_sizes[0] / d;          // 1024
    const int nb_train = in_sizes[3];              // 100000
    const int knm1     = in_sizes[4] / nb_train;   // 74
    const int nb_cali  = in_sizes[5];              // 1000

    const int Mp = (B + 127) & ~127;               // 1024
    const int Np = (nb_train + 127) & ~127;        // 100096
    const int ng64 = Np >> 6;                      // 1564

    char* ws = (char*)d_ws;
    size_t off = 0;
    float* gmin = (float*)(ws + off);          off += (size_t)Mp * ng64 * 4;
    unsigned short* Ah = (unsigned short*)(ws + off); off += (size_t)Mp * 256 * 2;
    float* xqf  = (float*)(ws + off);          off += (size_t)Mp * 256 * 4;
    float* q2a  = (float*)(ws + off);          off += (size_t)Mp * 4;
    float* al2q = (float*)(ws + off);          off += (size_t)Mp * 4;
    unsigned short* Bh = (unsigned short*)(ws + off); off += (size_t)Np * 256 * 2;
    float* xn2  = (float*)(ws + off);          off += (size_t)Np * 4;
    unsigned int* scal = (unsigned int*)(ws + off); off += 8;

    hipMemsetAsync(scal, 0, 8, stream);

    const int train_rb = Np / 16;                  // 6256
    prep_all<<<train_rb + Mp, 256, 0, stream>>>(
        X, x, center, Bh, xn2, Ah, xqf, q2a, al2q, scal,
        nb_train, Np, B, Mp, train_rb);

    const int ntiles = Np / 128;                   // 782
    const int mtiles = Mp / 128;                   // 8
    const int nper   = (ntiles + 7) / 8;           // 98
    mfma_tile<<<8 * nper * mtiles, 256, 0, stream>>>(
        Ah, Bh, xn2, gmin, Mp, Np, nb_train, B, ntiles, nper, mtiles);

    select_classify<<<B, 256, ng64 * 4, stream>>>(
        gmin, xqf, X, xn2, q2a, al2q, scal, labels, nbr, cali, out,
        Np, nb_train, knm1, nb_cali, B);
}